// Round 10
// baseline (38.900 us; speedup 1.0000x reference)
//
#include <hip/hip_runtime.h>
#include <hip/hip_bf16.h>

typedef __bf16 bf16x8 __attribute__((ext_vector_type(8)));
typedef float  f32x4  __attribute__((ext_vector_type(4)));

constexpr int B = 8, N = 4096, T = 128, D = 32;
constexpr float GAMMA = 0.001f;
constexpr float LOG2E = 1.4426950408889634f;
constexpr float K2 = -GAMMA * LOG2E;   // coeff on sq1 / sq2 (log2 domain)
constexpr float M2 = -2.0f * K2;       // coeff on dot

__device__ __forceinline__ float exp2_fast(float t) {
#if __has_builtin(__builtin_amdgcn_exp2f)
  return __builtin_amdgcn_exp2f(t);
#else
  return exp2f(t);
#endif
}

// deg-3 minimax for 2^t on [-2, 0]; abs err ~6.5e-4 (t provably in-range).
__device__ __forceinline__ float exp2_poly(float t) {
  return fmaf(fmaf(fmaf(0.0285860f, t, 0.2107500f), t, 0.6821055f), t,
              0.9993455f);
}

// ---------------------------------------------------------------------------
// Kernel 1 (MFMA proj): unchanged from r3-r9 (~7 us).
// ---------------------------------------------------------------------------
__global__ __launch_bounds__(256, 2) void proj_mfma(
    const float* __restrict__ x,  const float* __restrict__ W1,
    const float* __restrict__ b1, const float* __restrict__ W2,
    const float* __restrict__ b2,
    __bf16* __restrict__ p1b, __bf16* __restrict__ p2b,
    float* __restrict__ s1, float* __restrict__ e2) {
  __shared__ bf16x8 wlds[4][4][64];   // 16 KB, frag-ready
  const int tid  = threadIdx.x;
  const int lane = tid & 63;
  const int wid  = tid >> 6;
  const int lr   = lane & 15;
  const int lk   = lane >> 4;
  const int r0   = blockIdx.x * 64 + wid * 16;   // 0 .. B*N-1

  #pragma unroll
  for (int t = 0; t < 4; ++t) {
    const int e  = tid + t * 256;
    const int c  = e >> 8;
    const int s  = (e >> 6) & 3;
    const int ln = e & 63;
    const int llr = ln & 15, llk = ln >> 4;
    const float* Wp = (c < 2) ? W1 : W2;
    const int cc = (c * 16 + llr) & 31;
    bf16x8 v;
    #pragma unroll
    for (int j = 0; j < 8; ++j)
      v[j] = (__bf16)Wp[(s * 32 + llk * 8 + j) * D + cc];
    wlds[c][s][ln] = v;
  }
  __syncthreads();

  bf16x8 wf[4][4];
  #pragma unroll
  for (int c = 0; c < 4; ++c)
    #pragma unroll
    for (int s = 0; s < 4; ++s)
      wf[c][s] = wlds[c][s][lane];

  bf16x8 af[4];
  const float* xr = x + (size_t)(r0 + lr) * T;
  #pragma unroll
  for (int s = 0; s < 4; ++s) {
    const int t0 = s * 32 + lk * 8;
    const f32x4 v0 = *reinterpret_cast<const f32x4*>(xr + t0);
    const f32x4 v1 = *reinterpret_cast<const f32x4*>(xr + t0 + 4);
    #pragma unroll
    for (int j = 0; j < 4; ++j) {
      af[s][j]     = (__bf16)v0[j];
      af[s][4 + j] = (__bf16)v1[j];
    }
  }

  f32x4 pv[4];
  #pragma unroll
  for (int c = 0; c < 4; ++c) {
    const float* bp = (c < 2) ? b1 : b2;
    const float bv = bp[(c * 16 + lr) & 31];
    f32x4 accv = {bv, bv, bv, bv};
    #pragma unroll
    for (int s = 0; s < 4; ++s)
      accv = __builtin_amdgcn_mfma_f32_16x16x32_bf16(af[s], wf[c][s], accv, 0, 0, 0);
    pv[c] = accv;
  }

  #pragma unroll
  for (int c = 0; c < 2; ++c)
    #pragma unroll
    for (int r = 0; r < 4; ++r)
      p1b[(size_t)(r0 + lk * 4 + r) * D + c * 16 + lr] = (__bf16)(M2 * pv[c][r]);
  #pragma unroll
  for (int c = 2; c < 4; ++c)
    #pragma unroll
    for (int r = 0; r < 4; ++r)
      p2b[(size_t)(r0 + lk * 4 + r) * D + (c - 2) * 16 + lr] = (__bf16)pv[c][r];

  float q1[4], q2[4];
  #pragma unroll
  for (int r = 0; r < 4; ++r) {
    q1[r] = fmaf(pv[0][r], pv[0][r], pv[1][r] * pv[1][r]);
    q2[r] = fmaf(pv[2][r], pv[2][r], pv[3][r] * pv[3][r]);
  }
  #pragma unroll
  for (int m = 1; m < 16; m <<= 1)
    #pragma unroll
    for (int r = 0; r < 4; ++r) {
      q1[r] += __shfl_xor(q1[r], m, 64);
      q2[r] += __shfl_xor(q2[r], m, 64);
    }
  if (lr == 0) {
    #pragma unroll
    for (int r = 0; r < 4; ++r) {
      const int row = r0 + lk * 4 + r;
      s1[row] = K2 * q1[r];
      e2[row] = 0.125f * exp2_fast(K2 * q2[r]);
    }
  }
}

// ---------------------------------------------------------------------------
// Kernel 2 v10: r9's read-once structure + TWO row-tiles per block with
// store/compute overlap and a single barrier.
//   stage B/S/E + loadA(t0) -> sync -> compute(t0) -> loadA(t1) ->
//   store(t0) -> compute(t1) -> store(t1)
// No barrier in the tile loop (syncthreads would drain the store queue);
// t0's store drain overlaps t1's loads+compute. B-panel staged once per
// 256 output rows (read traffic halved vs r9). Same-j0 blocks share an XCD
// (grid id stride 64 % 8 == 0) so the B-panel stays L2-local.
// ---------------------------------------------------------------------------
__global__ __launch_bounds__(256, 3) void fused_kernel(
    const __bf16* __restrict__ p1b, const __bf16* __restrict__ p2b,
    const float* __restrict__ s1,   const float* __restrict__ e2,
    float* __restrict__ out) {
  __shared__ __align__(16) __bf16 LB[B * 64 * 32];  // 32 KB, swizzled slots
  __shared__ __align__(16) float  LS[B][256];       // 8 KB (both tiles)
  __shared__ __align__(16) float  LE[B * 64];       // 2 KB

  const int tid  = threadIdx.x;
  const int lane = tid & 63;
  const int wid  = tid >> 6;
  const int j0 = blockIdx.x * 64;                // col base (block)
  const int i0blk = blockIdx.y * 256;            // row base (block, 2 tiles)
  const int lr = lane & 15;
  const int lk = lane >> 4;

  // ---- A-fragments for tile 0 (issue first; overlaps staging drain) ----
  bf16x8 A0[B][2];
  #pragma unroll
  for (int b = 0; b < B; ++b)
    #pragma unroll
    for (int a = 0; a < 2; ++a)
      A0[b][a] = *reinterpret_cast<const bf16x8*>(
          p1b + ((size_t)b * N + i0blk + wid * 32 + a * 16 + lr) * D + lk * 8);

  // ---- stage B (swizzled), S (both tiles), E ----
  #pragma unroll
  for (int q = 0; q < 8; ++q) {
    const int g   = tid + q * 256;
    const int b   = g >> 8;
    const int c8  = g & 255;
    const int row = c8 >> 2;
    const int sl  = c8 & 3;
    const bf16x8 v = *reinterpret_cast<const bf16x8*>(
        p2b + ((size_t)b * N + j0 + row) * D + sl * 8);
    const int su = sl ^ ((row >> 1) & 3);
    *reinterpret_cast<bf16x8*>(&LB[(((b << 6) + row) << 2 | su) << 3]) = v;
  }
  {
    const int b = tid >> 5, o = (tid & 31) * 8;
    *reinterpret_cast<f32x4*>(&LS[b][o]) =
        *reinterpret_cast<const f32x4*>(s1 + (size_t)b * N + i0blk + o);
    *reinterpret_cast<f32x4*>(&LS[b][o + 4]) =
        *reinterpret_cast<const f32x4*>(s1 + (size_t)b * N + i0blk + o + 4);
  }
  if (tid < 128) {
    const int b = tid >> 4, o = (tid & 15) * 4;
    *reinterpret_cast<f32x4*>(&LE[b * 64 + o]) =
        *reinterpret_cast<const f32x4*>(e2 + (size_t)b * N + j0 + o);
  }

  __syncthreads();

  f32x4 acc[2][4];
  const int sub = lk ^ ((lr >> 1) & 3);   // B-read swizzle (c*16 keeps bits)

  auto compute = [&](const bf16x8 (&A)[B][2], int t)
      __attribute__((always_inline)) {
    #pragma unroll
    for (int b = 0; b < B; ++b) {
      bf16x8 Bf[4];
      #pragma unroll
      for (int c = 0; c < 4; ++c)
        Bf[c] = *reinterpret_cast<const bf16x8*>(
            &LB[(((b << 6) + c * 16 + lr) << 2 | sub) << 3]);
      f32x4 S[2];
      #pragma unroll
      for (int a = 0; a < 2; ++a)
        S[a] = *reinterpret_cast<const f32x4*>(
            &LS[b][t * 128 + wid * 32 + a * 16 + lk * 4]);
      float E[4];
      #pragma unroll
      for (int c = 0; c < 4; ++c)
        E[c] = LE[b * 64 + c * 16 + lr];

      #pragma unroll
      for (int a = 0; a < 2; ++a) {
        #pragma unroll
        for (int c = 0; c < 4; ++c) {
          f32x4 tt = __builtin_amdgcn_mfma_f32_16x16x32_bf16(
              A[b][a], Bf[c], S[a], 0, 0, 0);
          #pragma unroll
          for (int r = 0; r < 4; ++r)
            acc[a][c][r] = fmaf(E[c], exp2_poly(tt[r]), acc[a][c][r]);
        }
      }
    }
  };

  auto store_tile = [&](int t) __attribute__((always_inline)) {
    const int i0 = i0blk + t * 128 + wid * 32;
    const bool hasdiag = (i0 < j0 + 64) && (j0 < i0 + 32);
    #pragma unroll
    for (int a = 0; a < 2; ++a) {
      #pragma unroll
      for (int c = 0; c < 4; ++c) {
        #pragma unroll
        for (int r = 0; r < 4; ++r) {
          const int row = i0 + a * 16 + lk * 4 + r;
          const int col = j0 + c * 16 + lr;
          float v = acc[a][c][r];
          if (hasdiag && row == col) v = 0.1f;
          out[(size_t)row * N + col] = v;
        }
      }
    }
  };

  // ---- tile 0 ----
  #pragma unroll
  for (int a = 0; a < 2; ++a)
    #pragma unroll
    for (int c = 0; c < 4; ++c)
      acc[a][c] = f32x4{0.f, 0.f, 0.f, 0.f};
  compute(A0, 0);

  // A-fragments for tile 1 (issued before t0 stores; latency hides under them)
  bf16x8 A1[B][2];
  #pragma unroll
  for (int b = 0; b < B; ++b)
    #pragma unroll
    for (int a = 0; a < 2; ++a)
      A1[b][a] = *reinterpret_cast<const bf16x8*>(
          p1b + ((size_t)b * N + i0blk + 128 + wid * 32 + a * 16 + lr) * D +
          lk * 8);

  store_tile(0);

  // ---- tile 1 ----
  #pragma unroll
  for (int a = 0; a < 2; ++a)
    #pragma unroll
    for (int c = 0; c < 4; ++c)
      acc[a][c] = f32x4{0.f, 0.f, 0.f, 0.f};
  compute(A1, 1);
  store_tile(1);
}

extern "C" void kernel_launch(void* const* d_in, const int* in_sizes, int n_in,
                              void* d_out, int out_size, void* d_ws, size_t ws_size,
                              hipStream_t stream) {
  (void)in_sizes; (void)n_in; (void)out_size; (void)ws_size;
  const float* x  = (const float*)d_in[0];
  const float* W1 = (const float*)d_in[1];
  const float* b1 = (const float*)d_in[2];
  const float* W2 = (const float*)d_in[3];
  const float* b2 = (const float*)d_in[4];
  float* out = (float*)d_out;

  char* ws = (char*)d_ws;
  const size_t pbytes = (size_t)B * N * D * sizeof(__bf16);  // 2 MB each
  __bf16* p1b = (__bf16*)ws;
  __bf16* p2b = (__bf16*)(ws + pbytes);
  float*  s1  = (float*)(ws + 2 * pbytes);
  float*  e2  = (float*)(ws + 2 * pbytes + (size_t)B * N * sizeof(float));

  proj_mfma<<<(B * N) / 64, 256, 0, stream>>>(x, W1, b1, W2, b2, p1b, p2b, s1, e2);

  dim3 grid(N / 64, N / 256);
  fused_kernel<<<grid, 256, 0, stream>>>(p1b, p2b, s1, e2, out);
}

// Round 11
// 37.651 us; speedup vs baseline: 1.0332x; 1.0332x over previous
//
#include <hip/hip_runtime.h>
#include <hip/hip_bf16.h>

typedef __bf16 bf16x8 __attribute__((ext_vector_type(8)));
typedef float  f32x4  __attribute__((ext_vector_type(4)));

constexpr int B = 8, N = 4096, T = 128, D = 32;
constexpr float GAMMA = 0.001f;
constexpr float LOG2E = 1.4426950408889634f;
constexpr float K2 = -GAMMA * LOG2E;   // coeff on sq1 / sq2 (log2 domain)
constexpr float M2 = -2.0f * K2;       // coeff on dot

__device__ __forceinline__ float exp2_fast(float t) {
#if __has_builtin(__builtin_amdgcn_exp2f)
  return __builtin_amdgcn_exp2f(t);
#else
  return exp2f(t);
#endif
}

// deg-3 minimax for 2^t on [-2, 0]; abs err ~6.5e-4 (t provably in-range).
__device__ __forceinline__ float exp2_poly(float t) {
  return fmaf(fmaf(fmaf(0.0285860f, t, 0.2107500f), t, 0.6821055f), t,
              0.9993455f);
}

// ---------------------------------------------------------------------------
// Kernel 1 (MFMA proj): unchanged from r3-r10 (~5 us).
// ---------------------------------------------------------------------------
__global__ __launch_bounds__(256, 2) void proj_mfma(
    const float* __restrict__ x,  const float* __restrict__ W1,
    const float* __restrict__ b1, const float* __restrict__ W2,
    const float* __restrict__ b2,
    __bf16* __restrict__ p1b, __bf16* __restrict__ p2b,
    float* __restrict__ s1, float* __restrict__ e2) {
  __shared__ bf16x8 wlds[4][4][64];   // 16 KB, frag-ready
  const int tid  = threadIdx.x;
  const int lane = tid & 63;
  const int wid  = tid >> 6;
  const int lr   = lane & 15;
  const int lk   = lane >> 4;
  const int r0   = blockIdx.x * 64 + wid * 16;   // 0 .. B*N-1

  #pragma unroll
  for (int t = 0; t < 4; ++t) {
    const int e  = tid + t * 256;
    const int c  = e >> 8;
    const int s  = (e >> 6) & 3;
    const int ln = e & 63;
    const int llr = ln & 15, llk = ln >> 4;
    const float* Wp = (c < 2) ? W1 : W2;
    const int cc = (c * 16 + llr) & 31;
    bf16x8 v;
    #pragma unroll
    for (int j = 0; j < 8; ++j)
      v[j] = (__bf16)Wp[(s * 32 + llk * 8 + j) * D + cc];
    wlds[c][s][ln] = v;
  }
  __syncthreads();

  bf16x8 wf[4][4];
  #pragma unroll
  for (int c = 0; c < 4; ++c)
    #pragma unroll
    for (int s = 0; s < 4; ++s)
      wf[c][s] = wlds[c][s][lane];

  bf16x8 af[4];
  const float* xr = x + (size_t)(r0 + lr) * T;
  #pragma unroll
  for (int s = 0; s < 4; ++s) {
    const int t0 = s * 32 + lk * 8;
    const f32x4 v0 = *reinterpret_cast<const f32x4*>(xr + t0);
    const f32x4 v1 = *reinterpret_cast<const f32x4*>(xr + t0 + 4);
    #pragma unroll
    for (int j = 0; j < 4; ++j) {
      af[s][j]     = (__bf16)v0[j];
      af[s][4 + j] = (__bf16)v1[j];
    }
  }

  f32x4 pv[4];
  #pragma unroll
  for (int c = 0; c < 4; ++c) {
    const float* bp = (c < 2) ? b1 : b2;
    const float bv = bp[(c * 16 + lr) & 31];
    f32x4 accv = {bv, bv, bv, bv};
    #pragma unroll
    for (int s = 0; s < 4; ++s)
      accv = __builtin_amdgcn_mfma_f32_16x16x32_bf16(af[s], wf[c][s], accv, 0, 0, 0);
    pv[c] = accv;
  }

  #pragma unroll
  for (int c = 0; c < 2; ++c)
    #pragma unroll
    for (int r = 0; r < 4; ++r)
      p1b[(size_t)(r0 + lk * 4 + r) * D + c * 16 + lr] = (__bf16)(M2 * pv[c][r]);
  #pragma unroll
  for (int c = 2; c < 4; ++c)
    #pragma unroll
    for (int r = 0; r < 4; ++r)
      p2b[(size_t)(r0 + lk * 4 + r) * D + (c - 2) * 16 + lr] = (__bf16)pv[c][r];

  float q1[4], q2[4];
  #pragma unroll
  for (int r = 0; r < 4; ++r) {
    q1[r] = fmaf(pv[0][r], pv[0][r], pv[1][r] * pv[1][r]);
    q2[r] = fmaf(pv[2][r], pv[2][r], pv[3][r] * pv[3][r]);
  }
  #pragma unroll
  for (int m = 1; m < 16; m <<= 1)
    #pragma unroll
    for (int r = 0; r < 4; ++r) {
      q1[r] += __shfl_xor(q1[r], m, 64);
      q2[r] += __shfl_xor(q2[r], m, 64);
    }
  if (lr == 0) {
    #pragma unroll
    for (int r = 0; r < 4; ++r) {
      const int row = r0 + lk * 4 + r;
      s1[row] = K2 * q1[r];
      e2[row] = 0.125f * exp2_fast(K2 * q2[r]);
    }
  }
}

// ---------------------------------------------------------------------------
// Kernel 2 v11: r9's read-once structure with HALVED wave tile (16x64) to
// eliminate register pressure.
// Theory: r9/r10's 64-128 VGPR of A-frags forced acc into AGPRs ->
// v_accvgpr_read/fma/v_accvgpr_write per epilogue op (~2x VALU) + only 12
// waves/CU left MFMA->poly dependency chains exposed. v11: A all-batches =
// 32 VGPR, acc = 16, total ~95 -> all-VGPR epilogue, LDS 36KB ->
// 4 blocks/CU = 16 waves/CU.
// ---------------------------------------------------------------------------
__global__ __launch_bounds__(256, 4) void fused_kernel(
    const __bf16* __restrict__ p1b, const __bf16* __restrict__ p2b,
    const float* __restrict__ s1,   const float* __restrict__ e2,
    float* __restrict__ out) {
  __shared__ __align__(16) __bf16 LB[B * 64 * 32];  // 32 KB, swizzled slots
  __shared__ __align__(16) float  LS[B * 64];       // 2 KB
  __shared__ __align__(16) float  LE[B * 64];       // 2 KB

  const int tid  = threadIdx.x;
  const int lane = tid & 63;
  const int wid  = tid >> 6;
  const int j0 = blockIdx.x * 64;                // col base (block)
  const int i0blk = blockIdx.y * 64;             // row base (block)
  const int i0 = i0blk + wid * 16;               // row base (wave)
  const int lr = lane & 15;
  const int lk = lane >> 4;

  // A-fragments, all 8 batches (32 VGPR), issued first
  bf16x8 A[B];
  #pragma unroll
  for (int b = 0; b < B; ++b)
    A[b] = *reinterpret_cast<const bf16x8*>(
        p1b + ((size_t)b * N + i0 + lr) * D + lk * 8);

  // stage B tiles -> LDS (swizzled): 2048 16B-chunks, 8 per thread
  #pragma unroll
  for (int q = 0; q < 8; ++q) {
    const int g   = tid + q * 256;
    const int b   = g >> 8;
    const int c8  = g & 255;
    const int row = c8 >> 2;
    const int sl  = c8 & 3;
    const bf16x8 v = *reinterpret_cast<const bf16x8*>(
        p2b + ((size_t)b * N + j0 + row) * D + sl * 8);
    const int su = sl ^ ((row >> 1) & 3);
    *reinterpret_cast<bf16x8*>(&LB[(((b << 6) + row) << 2 | su) << 3]) = v;
  }
  // stage S (threads 0-127) and E (threads 128-255): 512 floats each
  if (tid < 128) {
    const int b = tid >> 4, o = (tid & 15) * 4;
    *reinterpret_cast<f32x4*>(&LS[b * 64 + o]) =
        *reinterpret_cast<const f32x4*>(s1 + (size_t)b * N + i0blk + o);
  } else {
    const int t2 = tid - 128;
    const int b = t2 >> 4, o = (t2 & 15) * 4;
    *reinterpret_cast<f32x4*>(&LE[b * 64 + o]) =
        *reinterpret_cast<const f32x4*>(e2 + (size_t)b * N + j0 + o);
  }

  __syncthreads();

  f32x4 acc[4];
  #pragma unroll
  for (int c = 0; c < 4; ++c) acc[c] = f32x4{0.f, 0.f, 0.f, 0.f};

  const int sub = lk ^ ((lr >> 1) & 3);   // B-read swizzle (c*16 keeps bits)
  #pragma unroll
  for (int b = 0; b < B; ++b) {
    bf16x8 Bf[4];
    #pragma unroll
    for (int c = 0; c < 4; ++c)
      Bf[c] = *reinterpret_cast<const bf16x8*>(
          &LB[(((b << 6) + c * 16 + lr) << 2 | sub) << 3]);
    const f32x4 S = *reinterpret_cast<const f32x4*>(
        &LS[b * 64 + wid * 16 + lk * 4]);
    float E[4];
    #pragma unroll
    for (int c = 0; c < 4; ++c)
      E[c] = LE[b * 64 + c * 16 + lr];

    #pragma unroll
    for (int c = 0; c < 4; ++c) {
      f32x4 t = __builtin_amdgcn_mfma_f32_16x16x32_bf16(
          A[b], Bf[c], S, 0, 0, 0);
      #pragma unroll
      for (int r = 0; r < 4; ++r)
        acc[c][r] = fmaf(E[c], exp2_poly(t[r]), acc[c][r]);
    }
  }

  const bool hasdiag = (i0 < j0 + 64) && (j0 < i0 + 16);
  #pragma unroll
  for (int c = 0; c < 4; ++c) {
    #pragma unroll
    for (int r = 0; r < 4; ++r) {
      const int row = i0 + lk * 4 + r;
      const int col = j0 + c * 16 + lr;
      float v = acc[c][r];
      if (hasdiag && row == col) v = 0.1f;
      out[(size_t)row * N + col] = v;
    }
  }
}

extern "C" void kernel_launch(void* const* d_in, const int* in_sizes, int n_in,
                              void* d_out, int out_size, void* d_ws, size_t ws_size,
                              hipStream_t stream) {
  (void)in_sizes; (void)n_in; (void)out_size; (void)ws_size;
  const float* x  = (const float*)d_in[0];
  const float* W1 = (const float*)d_in[1];
  const float* b1 = (const float*)d_in[2];
  const float* W2 = (const float*)d_in[3];
  const float* b2 = (const float*)d_in[4];
  float* out = (float*)d_out;

  char* ws = (char*)d_ws;
  const size_t pbytes = (size_t)B * N * D * sizeof(__bf16);  // 2 MB each
  __bf16* p1b = (__bf16*)ws;
  __bf16* p2b = (__bf16*)(ws + pbytes);
  float*  s1  = (float*)(ws + 2 * pbytes);
  float*  e2  = (float*)(ws + 2 * pbytes + (size_t)B * N * sizeof(float));

  proj_mfma<<<(B * N) / 64, 256, 0, stream>>>(x, W1, b1, W2, b2, p1b, p2b, s1, e2);

  dim3 grid(N / 64, N / 64);
  fused_kernel<<<grid, 256, 0, stream>>>(p1b, p2b, s1, e2, out);
}